// Round 6
// baseline (325.268 us; speedup 1.0000x reference)
//
#include <hip/hip_runtime.h>
#include <math.h>

#define S 1024
#define D 64
#define NBH 64
#define NBINS 8192
#define NWORDS (NBINS / 2)
#define EPS 1e-5f

typedef __attribute__((ext_vector_type(8))) short short8;
typedef __attribute__((ext_vector_type(4))) float floatx4;

__device__ __forceinline__ int binof(float sim) {
    int b = (int)((sim + 1.0f) * (NBINS / 2));
    return b < 0 ? 0 : (b > NBINS - 1 ? NBINS - 1 : b);
}

__device__ __forceinline__ unsigned short f2bf(float f) {   // RNE f32->bf16
    unsigned u = __float_as_uint(f);
    u += 0x7fffu + ((u >> 16) & 1u);
    return (unsigned short)(u >> 16);
}
__device__ __forceinline__ float bf2f(unsigned short h) {
    return __uint_as_float(((unsigned)h) << 16);
}

// ---------------- norms + hi/lo bf16 split for Q and K ----------------
__global__ __launch_bounds__(256) void norms_kernel(
    const float* __restrict__ Q, const float* __restrict__ K,
    float* __restrict__ qinv, float* __restrict__ kinv,
    unsigned short* __restrict__ Qhi, unsigned short* __restrict__ Qlo,
    unsigned short* __restrict__ Khi, unsigned short* __restrict__ Klo)
{
    int tid = threadIdx.x;
    int grp = tid >> 4, lane = tid & 15;
    long long rowArea = (long long)NBH * S;
    long long row = (long long)blockIdx.x * 16 + grp;
    const float* src; float* dst; unsigned short *dhi, *dlo;
    if (row < rowArea) { src = Q; dst = qinv; dhi = Qhi; dlo = Qlo; }
    else               { src = K; dst = kinv; dhi = Khi; dlo = Klo; row -= rowArea; }
    float4 v = *(const float4*)(src + row * D + lane * 4);
    float s = v.x*v.x + v.y*v.y + v.z*v.z + v.w*v.w;
    s += __shfl_xor(s, 1);
    s += __shfl_xor(s, 2);
    s += __shfl_xor(s, 4);
    s += __shfl_xor(s, 8);
    if (lane == 0) dst[row] = 1.0f / (sqrtf(s) + EPS);

    float f[4] = {v.x, v.y, v.z, v.w};
    unsigned short hi[4], lo[4];
    #pragma unroll
    for (int j = 0; j < 4; j++) {
        hi[j] = f2bf(f[j]);
        lo[j] = f2bf(f[j] - bf2f(hi[j]));
    }
    *(ushort4*)(dhi + row * D + lane * 4) = *(ushort4*)hi;
    *(ushort4*)(dlo + row * D + lane * 4) = *(ushort4*)lo;
}

// ---------------- Vt: V [bh][S][D] f32 -> Vt [bh][D][S] bf16 ----------------
__global__ __launch_bounds__(256) void vt_kernel(
    const float* __restrict__ V, unsigned short* __restrict__ Vt)
{
    __shared__ float tile[64 * 68];
    int bh = blockIdx.x >> 4;
    int k0 = (blockIdx.x & 15) * 64;
    int t = threadIdx.x;
    int r = t >> 2, cg = (t & 3) * 16;
    const float* Vb = V + ((size_t)bh * S + k0) * D;
    #pragma unroll
    for (int j = 0; j < 4; j++) {
        float4 v = *(const float4*)(Vb + r * D + cg + j * 4);
        *(float4*)(&tile[r * 68 + cg + j * 4]) = v;
    }
    __syncthreads();
    unsigned short wb[16];
    #pragma unroll
    for (int j = 0; j < 16; j++) wb[j] = f2bf(tile[(cg + j) * 68 + r]);
    unsigned short* dst = Vt + ((size_t)bh * D + r) * S + k0 + cg;
    *(uint4*)(dst)     = *(uint4*)(wb);
    *(uint4*)(dst + 8) = *(uint4*)(wb + 8);
}

// ---------------- pass 1: histogram only (no key stores) ----------------
// block = 128q x 512k strip (loop 4 k-tiles of 128). 16 blocks/bh, all bh at once.
__global__ __launch_bounds__(256) void hist_kernel(
    const unsigned short* __restrict__ Qhi, const unsigned short* __restrict__ Qlo,
    const unsigned short* __restrict__ Khi, const unsigned short* __restrict__ Klo,
    const float* __restrict__ qinv, const float* __restrict__ kinv,
    unsigned* __restrict__ hist)
{
    __shared__ unsigned hist_s[NWORDS];   // 16 KB packed u16 pairs
    int bh   = blockIdx.x >> 4;
    int tile = blockIdx.x & 15;
    int q0     = (tile >> 1) * 128;
    int kstrip = (tile & 1) * 512;
    int t = threadIdx.x;

    #pragma unroll
    for (int i = t; i < NWORDS / 4; i += 256) ((uint4*)hist_s)[i] = make_uint4(0,0,0,0);

    int wv = t >> 6, lane = t & 63, col = lane & 15, kgrp = lane >> 4;
    const unsigned short* qhb = Qhi + ((size_t)bh * S + q0 + wv * 32) * D;
    const unsigned short* qlb = Qlo + ((size_t)bh * S + q0 + wv * 32) * D;

    float qv[2][4];
    #pragma unroll
    for (int qs = 0; qs < 2; qs++)
        #pragma unroll
        for (int r = 0; r < 4; r++)
            qv[qs][r] = qinv[(size_t)bh * S + q0 + wv * 32 + qs * 16 + kgrp * 4 + r];

    __syncthreads();   // hist_s zeroed

    for (int kt = 0; kt < 4; kt++) {
        int k0 = kstrip + kt * 128;
        const unsigned short* khb = Khi + ((size_t)bh * S + k0) * D;
        const unsigned short* klb = Klo + ((size_t)bh * S + k0) * D;

        floatx4 acc[2][8] = {};
        #pragma unroll
        for (int ks = 0; ks < 2; ks++) {
            int doff = ks * 32 + kgrp * 8;
            short8 ah[2], al[2];
            #pragma unroll
            for (int qs = 0; qs < 2; qs++) {
                ah[qs] = *(const short8*)(qhb + (qs * 16 + col) * D + doff);
                al[qs] = *(const short8*)(qlb + (qs * 16 + col) * D + doff);
            }
            #pragma unroll
            for (int n = 0; n < 8; n++) {
                short8 bh8 = *(const short8*)(khb + (n * 16 + col) * D + doff);
                short8 bl8 = *(const short8*)(klb + (n * 16 + col) * D + doff);
                #pragma unroll
                for (int qs = 0; qs < 2; qs++) {
                    acc[qs][n] = __builtin_amdgcn_mfma_f32_16x16x32_bf16(ah[qs], bh8, acc[qs][n], 0, 0, 0);
                    acc[qs][n] = __builtin_amdgcn_mfma_f32_16x16x32_bf16(ah[qs], bl8, acc[qs][n], 0, 0, 0);
                    acc[qs][n] = __builtin_amdgcn_mfma_f32_16x16x32_bf16(al[qs], bh8, acc[qs][n], 0, 0, 0);
                }
            }
        }

        float kvv[8];
        #pragma unroll
        for (int n = 0; n < 8; n++)
            kvv[n] = kinv[(size_t)bh * S + k0 + n * 16 + col];
        #pragma unroll
        for (int qs = 0; qs < 2; qs++) {
            #pragma unroll
            for (int n = 0; n < 8; n++) {
                floatx4 a = acc[qs][n];
                #pragma unroll
                for (int r = 0; r < 4; r++) {
                    float sc = a[r] * qv[qs][r] * kvv[n];
                    int b = binof(sc);
                    atomicAdd(&hist_s[b >> 1], 1u << ((b & 1) << 4));
                }
            }
        }
    }
    __syncthreads();

    unsigned* hb = hist + (size_t)bh * NWORDS;
    #pragma unroll
    for (int i = t; i < NWORDS; i += 256) {
        unsigned v = hist_s[i];
        if (v) atomicAdd(&hb[i], v);
    }
}

// ---------------- weight table: unpack + suffix scan + lgamma bin-average ----------------
__global__ __launch_bounds__(1024) void table_kernel(
    const unsigned* __restrict__ hist, float* __restrict__ wtab)
{
    __shared__ unsigned ssum[1024];
    int tid = threadIdx.x;
    const unsigned* h = hist + (size_t)blockIdx.x * NWORDS;
    float* wt = wtab + (size_t)blockIdx.x * NBINS;

    unsigned c[8];
    unsigned tot = 0;
    #pragma unroll
    for (int j = 0; j < 4; j++) {
        unsigned w = h[tid * 4 + j];
        c[2*j]   = w & 0xffffu;
        c[2*j+1] = w >> 16;
        tot += c[2*j] + c[2*j+1];
    }
    ssum[tid] = tot;
    __syncthreads();
    for (int ofs = 1; ofs < 1024; ofs <<= 1) {
        unsigned v = ssum[tid] + ((tid + ofs < 1024) ? ssum[tid + ofs] : 0u);
        __syncthreads();
        ssum[tid] = v;
        __syncthreads();
    }
    unsigned run = (tid < 1023) ? ssum[tid + 1] : 0u;

    const double ln_n = 13.862943611198906; // ln(1048576)
    #pragma unroll
    for (int i = 7; i >= 0; i--) {
        unsigned ci = c[i];
        float w = 0.0f;
        if (ci) {
            double b = (double)run, e = (double)(run + ci);
            double val = (double)ci * ln_n - (lgamma(e + 1.0) - lgamma(b + 1.0));
            w = (float)(val / (double)ci);
        }
        wt[tid * 8 + i] = w;
        run += ci;
    }
}

// ---------------- pass 2 (fused): recompute scores -> W -> out = (W/rowsum)@V ----------------
// block = 64 q-rows; wave wv owns rows [wv*16, wv*16+16). Score MFMA chain is
// bit-identical to hist_kernel, so binning matches exactly.
__global__ __launch_bounds__(256) void fused_kernel(
    const unsigned short* __restrict__ Qhi, const unsigned short* __restrict__ Qlo,
    const unsigned short* __restrict__ Khi, const unsigned short* __restrict__ Klo,
    const float* __restrict__ qinv, const float* __restrict__ kinv,
    const float* __restrict__ wtab, const unsigned short* __restrict__ Vt,
    float* __restrict__ out)
{
    __shared__ float wt_s[NBINS];                         // 32 KB
    __shared__ __align__(16) unsigned short Ws[64 * 64];  // 8 KB bf16, XOR-swizzled
    int bh = blockIdx.x >> 4;
    int q0 = (blockIdx.x & 15) * 64;
    int t = threadIdx.x;

    const float* wtg = wtab + (size_t)bh * NBINS;
    #pragma unroll
    for (int i = t; i < NBINS / 4; i += 256)
        ((float4*)wt_s)[i] = ((const float4*)wtg)[i];

    int wv = t >> 6, lane = t & 63, col = lane & 15, kgrp = lane >> 4;
    const unsigned short* qhb = Qhi + ((size_t)bh * S + q0 + wv * 16) * D;
    const unsigned short* qlb = Qlo + ((size_t)bh * S + q0 + wv * 16) * D;
    const unsigned short* khb = Khi + (size_t)bh * S * D;
    const unsigned short* klb = Klo + (size_t)bh * S * D;
    const unsigned short* vb  = Vt + (size_t)bh * D * S;

    short8 qh[2], ql[2];
    #pragma unroll
    for (int ks = 0; ks < 2; ks++) {
        int doff = ks * 32 + kgrp * 8;
        qh[ks] = *(const short8*)(qhb + col * D + doff);
        ql[ks] = *(const short8*)(qlb + col * D + doff);
    }
    float qvr[4];
    #pragma unroll
    for (int r = 0; r < 4; r++)
        qvr[r] = qinv[(size_t)bh * S + q0 + wv * 16 + kgrp * 4 + r];

    floatx4 oacc[4] = {};
    float rs[4] = {0.f, 0.f, 0.f, 0.f};

    __syncthreads();   // wt_s ready

    for (int k0 = 0; k0 < S; k0 += 64) {
        // --- scores (identical chain to hist_kernel) ---
        floatx4 sacc[4] = {};
        #pragma unroll
        for (int ks = 0; ks < 2; ks++) {
            int doff = ks * 32 + kgrp * 8;
            #pragma unroll
            for (int n = 0; n < 4; n++) {
                short8 bh8 = *(const short8*)(khb + (size_t)(k0 + n * 16 + col) * D + doff);
                short8 bl8 = *(const short8*)(klb + (size_t)(k0 + n * 16 + col) * D + doff);
                sacc[n] = __builtin_amdgcn_mfma_f32_16x16x32_bf16(qh[ks], bh8, sacc[n], 0, 0, 0);
                sacc[n] = __builtin_amdgcn_mfma_f32_16x16x32_bf16(qh[ks], bl8, sacc[n], 0, 0, 0);
                sacc[n] = __builtin_amdgcn_mfma_f32_16x16x32_bf16(ql[ks], bh8, sacc[n], 0, 0, 0);
            }
        }

        // --- bin -> weight -> transpose via per-wave-private swizzled LDS ---
        float kvn[4];
        #pragma unroll
        for (int n = 0; n < 4; n++)
            kvn[n] = kinv[(size_t)bh * S + k0 + n * 16 + col];

        __syncthreads();   // all waves done reading Ws from previous tile
        #pragma unroll
        for (int n = 0; n < 4; n++) {
            #pragma unroll
            for (int r = 0; r < 4; r++) {
                float sc = sacc[n][r] * qvr[r] * kvn[n];
                int b = binof(sc);
                float w = wt_s[b];
                rs[r] += w;
                int ql_ = wv * 16 + kgrp * 4 + r;
                unsigned byte = (unsigned)(ql_ * 128 + (n * 16 + col) * 2)
                              ^ (unsigned)((ql_ & 7) << 4);
                *(unsigned short*)((char*)Ws + byte) = f2bf(w);
            }
        }
        __syncthreads();   // Ws ready

        #pragma unroll
        for (int ks = 0; ks < 2; ks++) {
            int grow = wv * 16 + col;
            unsigned abyte = (unsigned)(grow * 128 + ks * 64 + kgrp * 16)
                           ^ (unsigned)((grow & 7) << 4);
            short8 a = *(const short8*)((const char*)Ws + abyte);
            #pragma unroll
            for (int n = 0; n < 4; n++) {
                short8 b = *(const short8*)(vb + (size_t)(n * 16 + col) * S
                                            + k0 + ks * 32 + kgrp * 8);
                oacc[n] = __builtin_amdgcn_mfma_f32_16x16x32_bf16(a, b, oacc[n], 0, 0, 0);
            }
        }
    }

    // rowsum: reduce across the 16 lanes sharing kgrp (cols)
    #pragma unroll
    for (int r = 0; r < 4; r++) {
        rs[r] += __shfl_xor(rs[r], 1);
        rs[r] += __shfl_xor(rs[r], 2);
        rs[r] += __shfl_xor(rs[r], 4);
        rs[r] += __shfl_xor(rs[r], 8);
    }

    #pragma unroll
    for (int r = 0; r < 4; r++) {
        float inv = 1.0f / rs[r];
        int q = q0 + wv * 16 + kgrp * 4 + r;
        #pragma unroll
        for (int n = 0; n < 4; n++)
            out[((size_t)bh * S + q) * D + n * 16 + col] = oacc[n][r] * inv;
    }
}

extern "C" void kernel_launch(void* const* d_in, const int* in_sizes, int n_in,
                              void* d_out, int out_size, void* d_ws, size_t ws_size,
                              hipStream_t stream) {
    const float* Q = (const float*)d_in[0];
    const float* K = (const float*)d_in[1];
    const float* V = (const float*)d_in[2];
    float* out = (float*)d_out;

    char* w = (char*)d_ws;
    float* qinv = (float*)w;
    float* kinv = qinv + NBH * S;
    size_t off = (size_t)2 * NBH * S * sizeof(float);
    unsigned short* Qhi = (unsigned short*)(w + off); off += (size_t)NBH * S * D * 2;
    unsigned short* Qlo = (unsigned short*)(w + off); off += (size_t)NBH * S * D * 2;
    unsigned short* Khi = (unsigned short*)(w + off); off += (size_t)NBH * S * D * 2;
    unsigned short* Klo = (unsigned short*)(w + off); off += (size_t)NBH * S * D * 2;
    unsigned short* Vt  = (unsigned short*)(w + off); off += (size_t)NBH * D * S * 2;
    unsigned* hist = (unsigned*)(w + off);            off += (size_t)NBH * NWORDS * 4;
    float* wtab = (float*)(w + off);                  off += (size_t)NBH * NBINS * 4;

    hipMemsetAsync(hist, 0, (size_t)NBH * NWORDS * 4, stream);
    norms_kernel<<<(2 * NBH * S) / 16, 256, 0, stream>>>(Q, K, qinv, kinv, Qhi, Qlo, Khi, Klo);
    vt_kernel<<<NBH * 16, 256, 0, stream>>>(V, Vt);
    hist_kernel<<<NBH * 16, 256, 0, stream>>>(Qhi, Qlo, Khi, Klo, qinv, kinv, hist);
    table_kernel<<<NBH, 1024, 0, stream>>>(hist, wtab);
    fused_kernel<<<NBH * 16, 256, 0, stream>>>(Qhi, Qlo, Khi, Klo, qinv, kinv, wtab, Vt, out);
}

// Round 7
// 319.007 us; speedup vs baseline: 1.0196x; 1.0196x over previous
//
#include <hip/hip_runtime.h>
#include <math.h>

#define S 1024
#define D 64
#define NBH 64
#define NBINS 8192
#define NWORDS (NBINS / 2)
#define EPS 1e-5f

typedef __attribute__((ext_vector_type(8))) short short8;
typedef __attribute__((ext_vector_type(4))) float floatx4;

__device__ __forceinline__ int binof(float sim) {
    int b = (int)((sim + 1.0f) * (NBINS / 2));
    return b < 0 ? 0 : (b > NBINS - 1 ? NBINS - 1 : b);
}

__device__ __forceinline__ unsigned short f2bf(float f) {   // RNE f32->bf16
    unsigned u = __float_as_uint(f);
    u += 0x7fffu + ((u >> 16) & 1u);
    return (unsigned short)(u >> 16);
}
__device__ __forceinline__ float bf2f(unsigned short h) {
    return __uint_as_float(((unsigned)h) << 16);
}

// ---------------- norms + hi/lo bf16 split for Q and K ----------------
__global__ __launch_bounds__(256) void norms_kernel(
    const float* __restrict__ Q, const float* __restrict__ K,
    float* __restrict__ qinv, float* __restrict__ kinv,
    unsigned short* __restrict__ Qhi, unsigned short* __restrict__ Qlo,
    unsigned short* __restrict__ Khi, unsigned short* __restrict__ Klo)
{
    int tid = threadIdx.x;
    int grp = tid >> 4, lane = tid & 15;
    long long rowArea = (long long)NBH * S;
    long long row = (long long)blockIdx.x * 16 + grp;
    const float* src; float* dst; unsigned short *dhi, *dlo;
    if (row < rowArea) { src = Q; dst = qinv; dhi = Qhi; dlo = Qlo; }
    else               { src = K; dst = kinv; dhi = Khi; dlo = Klo; row -= rowArea; }
    float4 v = *(const float4*)(src + row * D + lane * 4);
    float s = v.x*v.x + v.y*v.y + v.z*v.z + v.w*v.w;
    s += __shfl_xor(s, 1);
    s += __shfl_xor(s, 2);
    s += __shfl_xor(s, 4);
    s += __shfl_xor(s, 8);
    if (lane == 0) dst[row] = 1.0f / (sqrtf(s) + EPS);

    float f[4] = {v.x, v.y, v.z, v.w};
    unsigned short hi[4], lo[4];
    #pragma unroll
    for (int j = 0; j < 4; j++) {
        hi[j] = f2bf(f[j]);
        lo[j] = f2bf(f[j] - bf2f(hi[j]));
    }
    *(ushort4*)(dhi + row * D + lane * 4) = *(ushort4*)hi;
    *(ushort4*)(dlo + row * D + lane * 4) = *(ushort4*)lo;
}

// ---------------- Vt: V [bh][S][D] f32 -> Vt [bh][D][S] bf16 ----------------
__global__ __launch_bounds__(256) void vt_kernel(
    const float* __restrict__ V, unsigned short* __restrict__ Vt)
{
    __shared__ float tile[64 * 68];
    int bh = blockIdx.x >> 4;
    int k0 = (blockIdx.x & 15) * 64;
    int t = threadIdx.x;
    int r = t >> 2, cg = (t & 3) * 16;
    const float* Vb = V + ((size_t)bh * S + k0) * D;
    #pragma unroll
    for (int j = 0; j < 4; j++) {
        float4 v = *(const float4*)(Vb + r * D + cg + j * 4);
        *(float4*)(&tile[r * 68 + cg + j * 4]) = v;
    }
    __syncthreads();
    unsigned short wb[16];
    #pragma unroll
    for (int j = 0; j < 16; j++) wb[j] = f2bf(tile[(cg + j) * 68 + r]);
    unsigned short* dst = Vt + ((size_t)bh * D + r) * S + k0 + cg;
    *(uint4*)(dst)     = *(uint4*)(wb);
    *(uint4*)(dst + 8) = *(uint4*)(wb + 8);
}

// ---------------- pass 1: histogram only (no key stores) ----------------
__global__ __launch_bounds__(256) void hist_kernel(
    const unsigned short* __restrict__ Qhi, const unsigned short* __restrict__ Qlo,
    const unsigned short* __restrict__ Khi, const unsigned short* __restrict__ Klo,
    const float* __restrict__ qinv, const float* __restrict__ kinv,
    unsigned* __restrict__ hist)
{
    __shared__ unsigned hist_s[NWORDS];   // 16 KB packed u16 pairs
    int bid = blockIdx.x;
    int swzb = ((bid & 7) << 7) | (bid >> 3);   // XCD-grouped: nwg=1024
    int bh   = swzb >> 4;
    int tile = swzb & 15;
    int q0     = (tile >> 1) * 128;
    int kstrip = (tile & 1) * 512;
    int t = threadIdx.x;

    #pragma unroll
    for (int i = t; i < NWORDS / 4; i += 256) ((uint4*)hist_s)[i] = make_uint4(0,0,0,0);

    int wv = t >> 6, lane = t & 63, col = lane & 15, kgrp = lane >> 4;
    const unsigned short* qhb = Qhi + ((size_t)bh * S + q0 + wv * 32) * D;
    const unsigned short* qlb = Qlo + ((size_t)bh * S + q0 + wv * 32) * D;

    float qv[2][4];
    #pragma unroll
    for (int qs = 0; qs < 2; qs++)
        #pragma unroll
        for (int r = 0; r < 4; r++)
            qv[qs][r] = qinv[(size_t)bh * S + q0 + wv * 32 + qs * 16 + kgrp * 4 + r];

    __syncthreads();   // hist_s zeroed

    for (int kt = 0; kt < 4; kt++) {
        int k0 = kstrip + kt * 128;
        const unsigned short* khb = Khi + ((size_t)bh * S + k0) * D;
        const unsigned short* klb = Klo + ((size_t)bh * S + k0) * D;

        floatx4 acc[2][8] = {};
        #pragma unroll
        for (int ks = 0; ks < 2; ks++) {
            int doff = ks * 32 + kgrp * 8;
            short8 ah[2], al[2];
            #pragma unroll
            for (int qs = 0; qs < 2; qs++) {
                ah[qs] = *(const short8*)(qhb + (qs * 16 + col) * D + doff);
                al[qs] = *(const short8*)(qlb + (qs * 16 + col) * D + doff);
            }
            #pragma unroll
            for (int n = 0; n < 8; n++) {
                short8 bh8 = *(const short8*)(khb + (n * 16 + col) * D + doff);
                short8 bl8 = *(const short8*)(klb + (n * 16 + col) * D + doff);
                #pragma unroll
                for (int qs = 0; qs < 2; qs++) {
                    acc[qs][n] = __builtin_amdgcn_mfma_f32_16x16x32_bf16(ah[qs], bh8, acc[qs][n], 0, 0, 0);
                    acc[qs][n] = __builtin_amdgcn_mfma_f32_16x16x32_bf16(ah[qs], bl8, acc[qs][n], 0, 0, 0);
                    acc[qs][n] = __builtin_amdgcn_mfma_f32_16x16x32_bf16(al[qs], bh8, acc[qs][n], 0, 0, 0);
                }
            }
        }

        float kvv[8];
        #pragma unroll
        for (int n = 0; n < 8; n++)
            kvv[n] = kinv[(size_t)bh * S + k0 + n * 16 + col];
        #pragma unroll
        for (int qs = 0; qs < 2; qs++) {
            #pragma unroll
            for (int n = 0; n < 8; n++) {
                floatx4 a = acc[qs][n];
                #pragma unroll
                for (int r = 0; r < 4; r++) {
                    float sc = a[r] * qv[qs][r] * kvv[n];
                    int b = binof(sc);
                    atomicAdd(&hist_s[b >> 1], 1u << ((b & 1) << 4));
                }
            }
        }
    }
    __syncthreads();

    unsigned* hb = hist + (size_t)bh * NWORDS;
    #pragma unroll
    for (int i = t; i < NWORDS; i += 256) {
        unsigned v = hist_s[i];
        if (v) atomicAdd(&hb[i], v);
    }
}

// ---------------- weight table: unpack + suffix scan + lgamma bin-average ----------------
__global__ __launch_bounds__(1024) void table_kernel(
    const unsigned* __restrict__ hist, float* __restrict__ wtab)
{
    __shared__ unsigned ssum[1024];
    int tid = threadIdx.x;
    const unsigned* h = hist + (size_t)blockIdx.x * NWORDS;
    float* wt = wtab + (size_t)blockIdx.x * NBINS;

    unsigned c[8];
    unsigned tot = 0;
    #pragma unroll
    for (int j = 0; j < 4; j++) {
        unsigned w = h[tid * 4 + j];
        c[2*j]   = w & 0xffffu;
        c[2*j+1] = w >> 16;
        tot += c[2*j] + c[2*j+1];
    }
    ssum[tid] = tot;
    __syncthreads();
    for (int ofs = 1; ofs < 1024; ofs <<= 1) {
        unsigned v = ssum[tid] + ((tid + ofs < 1024) ? ssum[tid + ofs] : 0u);
        __syncthreads();
        ssum[tid] = v;
        __syncthreads();
    }
    unsigned run = (tid < 1023) ? ssum[tid + 1] : 0u;

    const double ln_n = 13.862943611198906; // ln(1048576)
    #pragma unroll
    for (int i = 7; i >= 0; i--) {
        unsigned ci = c[i];
        float w = 0.0f;
        if (ci) {
            double b = (double)run, e = (double)(run + ci);
            double val = (double)ci * ln_n - (lgamma(e + 1.0) - lgamma(b + 1.0));
            w = (float)(val / (double)ci);
        }
        wt[tid * 8 + i] = w;
        run += ci;
    }
}

// ---------------- pass 2 (fused, barrier-free): S^T = mfma(K,Q); W; out=(W/rowsum)@V ----------------
// Swapped operands: lane owns q = lane&15, k-local = n*16 + grp*4 + r. Weight
// transpose goes through a per-wave-private swizzled 2 KB LDS tile (rows=col,
// disjoint per wave -> no __syncthreads in the main loop).
__global__ __launch_bounds__(256) void fused_kernel(
    const unsigned short* __restrict__ Qhi, const unsigned short* __restrict__ Qlo,
    const unsigned short* __restrict__ Khi, const unsigned short* __restrict__ Klo,
    const float* __restrict__ qinv, const float* __restrict__ kinv,
    const float* __restrict__ wtab, const unsigned short* __restrict__ Vt,
    float* __restrict__ out)
{
    __shared__ float wt_s[NBINS];                            // 32 KB
    __shared__ __align__(16) unsigned short Ws[4][16 * 64];  // 8 KB, per-wave private
    int bid = blockIdx.x;
    int swzb = ((bid & 7) << 7) | (bid >> 3);   // XCD-grouped: nwg=1024
    int bh = swzb >> 4;
    int q0 = (swzb & 15) * 64;
    int t = threadIdx.x;

    const float* wtg = wtab + (size_t)bh * NBINS;
    #pragma unroll
    for (int i = t; i < NBINS / 4; i += 256)
        ((float4*)wt_s)[i] = ((const float4*)wtg)[i];

    int wv = t >> 6, lane = t & 63, col = lane & 15, grp = lane >> 4;
    const unsigned short* qhb = Qhi + ((size_t)bh * S + q0 + wv * 16) * D;
    const unsigned short* qlb = Qlo + ((size_t)bh * S + q0 + wv * 16) * D;
    const unsigned short* khb = Khi + (size_t)bh * S * D;
    const unsigned short* klb = Klo + (size_t)bh * S * D;
    const unsigned short* vb  = Vt + (size_t)bh * D * S;
    const float* kvb = kinv + (size_t)bh * S;

    short8 qh[2], ql[2];
    #pragma unroll
    for (int ks = 0; ks < 2; ks++) {
        int doff = ks * 32 + grp * 8;
        qh[ks] = *(const short8*)(qhb + col * D + doff);
        ql[ks] = *(const short8*)(qlb + col * D + doff);
    }
    float qv = qinv[(size_t)bh * S + q0 + wv * 16 + col];

    char* wsbase = (char*)(&Ws[wv][0]);
    unsigned wrow = (unsigned)(col * 128);
    unsigned cxor = (unsigned)((col & 7) << 4);

    floatx4 oacc[4] = {};
    float rs = 0.f;

    __syncthreads();   // wt_s ready (only barrier in the kernel)

    for (int k0 = 0; k0 < S; k0 += 64) {
        // --- scores, swapped: sacc[n][r] = S[k = k0+n*16+grp*4+r][q = q0+wv*16+col]
        floatx4 sacc[4] = {};
        #pragma unroll
        for (int ks = 0; ks < 2; ks++) {
            int doff = ks * 32 + grp * 8;
            #pragma unroll
            for (int n = 0; n < 4; n++) {
                short8 kh8 = *(const short8*)(khb + (size_t)(k0 + n * 16 + col) * D + doff);
                short8 kl8 = *(const short8*)(klb + (size_t)(k0 + n * 16 + col) * D + doff);
                sacc[n] = __builtin_amdgcn_mfma_f32_16x16x32_bf16(kh8, qh[ks], sacc[n], 0, 0, 0);
                sacc[n] = __builtin_amdgcn_mfma_f32_16x16x32_bf16(kl8, qh[ks], sacc[n], 0, 0, 0);
                sacc[n] = __builtin_amdgcn_mfma_f32_16x16x32_bf16(kh8, ql[ks], sacc[n], 0, 0, 0);
            }
        }

        // --- bin -> weight -> pack 4 bf16 -> one b64 write into private swizzled tile
        #pragma unroll
        for (int n = 0; n < 4; n++) {
            float4 kv4 = *(const float4*)(kvb + k0 + n * 16 + grp * 4);
            float w0 = wt_s[binof(sacc[n][0] * qv * kv4.x)];
            float w1 = wt_s[binof(sacc[n][1] * qv * kv4.y)];
            float w2 = wt_s[binof(sacc[n][2] * qv * kv4.z)];
            float w3 = wt_s[binof(sacc[n][3] * qv * kv4.w)];
            rs += (w0 + w1) + (w2 + w3);
            unsigned p0 = (unsigned)f2bf(w0) | ((unsigned)f2bf(w1) << 16);
            unsigned p1 = (unsigned)f2bf(w2) | ((unsigned)f2bf(w3) << 16);
            unsigned addr = wrow + (((unsigned)(n * 32 + grp * 8)) ^ cxor);
            *(uint2*)(wsbase + addr) = make_uint2(p0, p1);
        }

        // --- PV: A = W row (own wave's rows), B = Vt fragment from global
        #pragma unroll
        for (int ks = 0; ks < 2; ks++) {
            unsigned raddr = wrow + (((unsigned)(ks * 64 + grp * 16)) ^ cxor);
            short8 a = *(const short8*)(wsbase + raddr);
            #pragma unroll
            for (int n = 0; n < 4; n++) {
                short8 b = *(const short8*)(vb + (size_t)(n * 16 + col) * S
                                            + k0 + ks * 32 + grp * 8);
                oacc[n] = __builtin_amdgcn_mfma_f32_16x16x32_bf16(a, b, oacc[n], 0, 0, 0);
            }
        }
    }

    // rowsum for q=col: reduce across the 4 grp groups
    rs += __shfl_xor(rs, 16);
    rs += __shfl_xor(rs, 32);
    // redistribute: output rows are q' = grp*4+r
    float inv[4];
    #pragma unroll
    for (int r = 0; r < 4; r++)
        inv[r] = 1.0f / __shfl(rs, (lane & 48) | (grp * 4 + r));

    #pragma unroll
    for (int r = 0; r < 4; r++) {
        int q = q0 + wv * 16 + grp * 4 + r;
        #pragma unroll
        for (int n = 0; n < 4; n++)
            out[((size_t)bh * S + q) * D + n * 16 + col] = oacc[n][r] * inv[r];
    }
}

extern "C" void kernel_launch(void* const* d_in, const int* in_sizes, int n_in,
                              void* d_out, int out_size, void* d_ws, size_t ws_size,
                              hipStream_t stream) {
    const float* Q = (const float*)d_in[0];
    const float* K = (const float*)d_in[1];
    const float* V = (const float*)d_in[2];
    float* out = (float*)d_out;

    char* w = (char*)d_ws;
    float* qinv = (float*)w;
    float* kinv = qinv + NBH * S;
    size_t off = (size_t)2 * NBH * S * sizeof(float);
    unsigned short* Qhi = (unsigned short*)(w + off); off += (size_t)NBH * S * D * 2;
    unsigned short* Qlo = (unsigned short*)(w + off); off += (size_t)NBH * S * D * 2;
    unsigned short* Khi = (unsigned short*)(w + off); off += (size_t)NBH * S * D * 2;
    unsigned short* Klo = (unsigned short*)(w + off); off += (size_t)NBH * S * D * 2;
    unsigned short* Vt  = (unsigned short*)(w + off); off += (size_t)NBH * D * S * 2;
    unsigned* hist = (unsigned*)(w + off);            off += (size_t)NBH * NWORDS * 4;
    float* wtab = (float*)(w + off);                  off += (size_t)NBH * NBINS * 4;

    hipMemsetAsync(hist, 0, (size_t)NBH * NWORDS * 4, stream);
    norms_kernel<<<(2 * NBH * S) / 16, 256, 0, stream>>>(Q, K, qinv, kinv, Qhi, Qlo, Khi, Klo);
    vt_kernel<<<NBH * 16, 256, 0, stream>>>(V, Vt);
    hist_kernel<<<NBH * 16, 256, 0, stream>>>(Qhi, Qlo, Khi, Klo, qinv, kinv, hist);
    table_kernel<<<NBH, 1024, 0, stream>>>(hist, wtab);
    fused_kernel<<<NBH * 16, 256, 0, stream>>>(Qhi, Qlo, Khi, Klo, qinv, kinv, wtab, Vt, out);
}

// Round 8
// 249.230 us; speedup vs baseline: 1.3051x; 1.2800x over previous
//
#include <hip/hip_runtime.h>
#include <math.h>

#define S 1024
#define D 64
#define NBH 64
#define NBINS 8192
#define NWORDS (NBINS / 2)
#define EPS 1e-5f

typedef __attribute__((ext_vector_type(8))) short short8;
typedef __attribute__((ext_vector_type(16))) float floatx16;

__device__ __forceinline__ int binof(float sim) {
    int b = (int)((sim + 1.0f) * (NBINS / 2));
    return b < 0 ? 0 : (b > NBINS - 1 ? NBINS - 1 : b);
}

__device__ __forceinline__ unsigned short f2bf(float f) {   // RNE f32->bf16
    unsigned u = __float_as_uint(f);
    u += 0x7fffu + ((u >> 16) & 1u);
    return (unsigned short)(u >> 16);
}
__device__ __forceinline__ float bf2f(unsigned short h) {
    return __uint_as_float(((unsigned)h) << 16);
}

// ---------------- norms + hi/lo bf16 split for Q and K ----------------
__global__ __launch_bounds__(256) void norms_kernel(
    const float* __restrict__ Q, const float* __restrict__ K,
    float* __restrict__ qinv, float* __restrict__ kinv,
    unsigned short* __restrict__ Qhi, unsigned short* __restrict__ Qlo,
    unsigned short* __restrict__ Khi, unsigned short* __restrict__ Klo)
{
    int tid = threadIdx.x;
    int grp = tid >> 4, lane = tid & 15;
    long long rowArea = (long long)NBH * S;
    long long row = (long long)blockIdx.x * 16 + grp;
    const float* src; float* dst; unsigned short *dhi, *dlo;
    if (row < rowArea) { src = Q; dst = qinv; dhi = Qhi; dlo = Qlo; }
    else               { src = K; dst = kinv; dhi = Khi; dlo = Klo; row -= rowArea; }
    float4 v = *(const float4*)(src + row * D + lane * 4);
    float s = v.x*v.x + v.y*v.y + v.z*v.z + v.w*v.w;
    s += __shfl_xor(s, 1);
    s += __shfl_xor(s, 2);
    s += __shfl_xor(s, 4);
    s += __shfl_xor(s, 8);
    if (lane == 0) dst[row] = 1.0f / (sqrtf(s) + EPS);

    float f[4] = {v.x, v.y, v.z, v.w};
    unsigned short hi[4], lo[4];
    #pragma unroll
    for (int j = 0; j < 4; j++) {
        hi[j] = f2bf(f[j]);
        lo[j] = f2bf(f[j] - bf2f(hi[j]));
    }
    *(ushort4*)(dhi + row * D + lane * 4) = *(ushort4*)hi;
    *(ushort4*)(dlo + row * D + lane * 4) = *(ushort4*)lo;
}

// ---------------- Vt: V [bh][S][D] f32 -> Vt [bh][D][S] bf16 ----------------
__global__ __launch_bounds__(256) void vt_kernel(
    const float* __restrict__ V, unsigned short* __restrict__ Vt)
{
    __shared__ float tile[64 * 68];
    int bh = blockIdx.x >> 4;
    int k0 = (blockIdx.x & 15) * 64;
    int t = threadIdx.x;
    int r = t >> 2, cg = (t & 3) * 16;
    const float* Vb = V + ((size_t)bh * S + k0) * D;
    #pragma unroll
    for (int j = 0; j < 4; j++) {
        float4 v = *(const float4*)(Vb + r * D + cg + j * 4);
        *(float4*)(&tile[r * 68 + cg + j * 4]) = v;
    }
    __syncthreads();
    unsigned short wb[16];
    #pragma unroll
    for (int j = 0; j < 16; j++) wb[j] = f2bf(tile[(cg + j) * 68 + r]);
    unsigned short* dst = Vt + ((size_t)bh * D + r) * S + k0 + cg;
    *(uint4*)(dst)     = *(uint4*)(wb);
    *(uint4*)(dst + 8) = *(uint4*)(wb + 8);
}

// ---------------- pass 1: histogram only ----------------
// block: 128q x 256k strip (2 kt-iters of 128). 32 blocks/bh -> grid 2048.
__global__ __launch_bounds__(256) void hist_kernel(
    const unsigned short* __restrict__ Qhi, const unsigned short* __restrict__ Qlo,
    const unsigned short* __restrict__ Khi, const unsigned short* __restrict__ Klo,
    const float* __restrict__ qinv, const float* __restrict__ kinv,
    unsigned* __restrict__ hist)
{
    typedef __attribute__((ext_vector_type(4))) float floatx4;
    __shared__ unsigned hist_s[NWORDS];   // 16 KB packed u16 pairs
    int bid = blockIdx.x;
    int swzb = (bid & 7) * 256 + (bid >> 3);   // nwg = 2048
    int bh   = swzb >> 5;
    int tile = swzb & 31;
    int q0     = (tile >> 2) * 128;
    int kstrip = (tile & 3) * 256;
    int t = threadIdx.x;

    #pragma unroll
    for (int i = t; i < NWORDS / 4; i += 256) ((uint4*)hist_s)[i] = make_uint4(0,0,0,0);

    int wv = t >> 6, lane = t & 63, col = lane & 15, kgrp = lane >> 4;
    const unsigned short* qhb = Qhi + ((size_t)bh * S + q0 + wv * 32) * D;
    const unsigned short* qlb = Qlo + ((size_t)bh * S + q0 + wv * 32) * D;

    float qv[2][4];
    #pragma unroll
    for (int qs = 0; qs < 2; qs++)
        #pragma unroll
        for (int r = 0; r < 4; r++)
            qv[qs][r] = qinv[(size_t)bh * S + q0 + wv * 32 + qs * 16 + kgrp * 4 + r];

    __syncthreads();   // hist_s zeroed

    for (int kt = 0; kt < 2; kt++) {
        int k0 = kstrip + kt * 128;
        const unsigned short* khb = Khi + ((size_t)bh * S + k0) * D;
        const unsigned short* klb = Klo + ((size_t)bh * S + k0) * D;

        floatx4 acc[2][8] = {};
        #pragma unroll
        for (int ks = 0; ks < 2; ks++) {
            int doff = ks * 32 + kgrp * 8;
            short8 ah[2], al[2];
            #pragma unroll
            for (int qs = 0; qs < 2; qs++) {
                ah[qs] = *(const short8*)(qhb + (qs * 16 + col) * D + doff);
                al[qs] = *(const short8*)(qlb + (qs * 16 + col) * D + doff);
            }
            #pragma unroll
            for (int n = 0; n < 8; n++) {
                short8 bh8 = *(const short8*)(khb + (n * 16 + col) * D + doff);
                short8 bl8 = *(const short8*)(klb + (n * 16 + col) * D + doff);
                #pragma unroll
                for (int qs = 0; qs < 2; qs++) {
                    acc[qs][n] = __builtin_amdgcn_mfma_f32_16x16x32_bf16(ah[qs], bh8, acc[qs][n], 0, 0, 0);
                    acc[qs][n] = __builtin_amdgcn_mfma_f32_16x16x32_bf16(ah[qs], bl8, acc[qs][n], 0, 0, 0);
                    acc[qs][n] = __builtin_amdgcn_mfma_f32_16x16x32_bf16(al[qs], bh8, acc[qs][n], 0, 0, 0);
                }
            }
        }

        float kvv[8];
        #pragma unroll
        for (int n = 0; n < 8; n++)
            kvv[n] = kinv[(size_t)bh * S + k0 + n * 16 + col];
        #pragma unroll
        for (int qs = 0; qs < 2; qs++) {
            #pragma unroll
            for (int n = 0; n < 8; n++) {
                floatx4 a = acc[qs][n];
                #pragma unroll
                for (int r = 0; r < 4; r++) {
                    float sc = a[r] * qv[qs][r] * kvv[n];
                    int b = binof(sc);
                    atomicAdd(&hist_s[b >> 1], 1u << ((b & 1) << 4));
                }
            }
        }
    }
    __syncthreads();

    unsigned* hb = hist + (size_t)bh * NWORDS;
    #pragma unroll
    for (int i = t; i < NWORDS; i += 256) {
        unsigned v = hist_s[i];
        if (v) atomicAdd(&hb[i], v);
    }
}

// ---------------- weight table (bf16) + empty-bin fill ----------------
__global__ __launch_bounds__(1024) void table_kernel(
    const unsigned* __restrict__ hist, unsigned short* __restrict__ wtab)
{
    __shared__ unsigned ssum[1024];
    int tid = threadIdx.x;
    const unsigned* h = hist + (size_t)blockIdx.x * NWORDS;
    unsigned short* wt = wtab + (size_t)blockIdx.x * NBINS;

    unsigned c[8];
    unsigned tot = 0;
    #pragma unroll
    for (int j = 0; j < 4; j++) {
        unsigned w = h[tid * 4 + j];
        c[2*j]   = w & 0xffffu;
        c[2*j+1] = w >> 16;
        tot += c[2*j] + c[2*j+1];
    }
    ssum[tid] = tot;
    __syncthreads();
    for (int ofs = 1; ofs < 1024; ofs <<= 1) {
        unsigned v = ssum[tid] + ((tid + ofs < 1024) ? ssum[tid + ofs] : 0u);
        __syncthreads();
        ssum[tid] = v;
        __syncthreads();
    }
    unsigned run = (tid < 1023) ? ssum[tid + 1] : 0u;

    const double ln_n = 13.862943611198906; // ln(1048576)
    #pragma unroll
    for (int i = 7; i >= 0; i--) {
        unsigned ci = c[i];
        float w;
        if (ci) {
            double b = (double)run, e = (double)(run + ci);
            double val = (double)ci * ln_n - (lgamma(e + 1.0) - lgamma(b + 1.0));
            w = (float)(val / (double)ci);
        } else {
            // empty bin: weight a hypothetical element at rank `run` would get
            w = (float)(ln_n - log((double)run + 1.0));
        }
        wt[tid * 8 + i] = f2bf(w);
        run += ci;
    }
}

// ---------------- pass 2 (fused): 32x32 scores -> register-forward PV ----------------
// Block = 4 waves sharing one 32-q tile; wave wv handles k in [wv*256, wv*256+256).
// Score: P^T = mfma_32x32x16(K, Q): lane (c=q, h) reg r holds k=(r&3)+8(r>>2)+4h.
// PV A-fragment (row=q=c, k=h*8+j) is built from score regs via shfl_xor(32)+select
// -- no LDS staging, no barriers in the main loop.
__global__ __launch_bounds__(256) void fused_kernel(
    const unsigned short* __restrict__ Qhi, const unsigned short* __restrict__ Qlo,
    const unsigned short* __restrict__ Khi, const unsigned short* __restrict__ Klo,
    const float* __restrict__ qinv, const float* __restrict__ kinv,
    const unsigned short* __restrict__ wtab, const unsigned short* __restrict__ Vt,
    float* __restrict__ out)
{
    __shared__ unsigned short wt_s[NBINS];   // 16 KB bf16
    __shared__ float zone[32 * 64];          // 8 KB merge buffer
    __shared__ float rsz[32];
    int bid = blockIdx.x;
    int swzb = (bid & 7) * 256 + (bid >> 3);   // nwg = 2048
    int bh = swzb >> 5;
    int q0 = (swzb & 31) * 32;
    int t = threadIdx.x;

    const uint4* wg = (const uint4*)(wtab + (size_t)bh * NBINS);
    #pragma unroll
    for (int i = t; i < NBINS / 8; i += 256) ((uint4*)wt_s)[i] = wg[i];

    int wv = t >> 6, lane = t & 63, c = lane & 31, h = lane >> 5;
    const unsigned short* qhb = Qhi + ((size_t)bh * S + q0 + c) * D;
    const unsigned short* qlb = Qlo + ((size_t)bh * S + q0 + c) * D;
    const unsigned short* khb = Khi + (size_t)bh * S * D;
    const unsigned short* klb = Klo + (size_t)bh * S * D;
    const unsigned short* vb  = Vt + (size_t)bh * D * S;
    const float* kvb = kinv + (size_t)bh * S;

    short8 qh[4], ql[4];
    #pragma unroll
    for (int s = 0; s < 4; s++) {
        qh[s] = *(const short8*)(qhb + s * 16 + h * 8);
        ql[s] = *(const short8*)(qlb + s * 16 + h * 8);
    }
    float qv = qinv[(size_t)bh * S + q0 + c];

    floatx16 oacc0 = {}, oacc1 = {};
    float rs = 0.f;

    __syncthreads();   // wt_s ready

    for (int it = 0; it < 8; it++) {
        int k0 = wv * 256 + it * 32;
        // --- scores: compensated bf16, 32x32x16 ---
        floatx16 sacc = {};
        #pragma unroll
        for (int s = 0; s < 4; s++) {
            const unsigned short* kr = khb + (size_t)(k0 + c) * D + s * 16 + h * 8;
            const unsigned short* lr = klb + (size_t)(k0 + c) * D + s * 16 + h * 8;
            short8 kh8 = *(const short8*)(kr);
            short8 kl8 = *(const short8*)(lr);
            sacc = __builtin_amdgcn_mfma_f32_32x32x16_bf16(kh8, qh[s], sacc, 0, 0, 0);
            sacc = __builtin_amdgcn_mfma_f32_32x32x16_bf16(kl8, qh[s], sacc, 0, 0, 0);
            sacc = __builtin_amdgcn_mfma_f32_32x32x16_bf16(kh8, ql[s], sacc, 0, 0, 0);
        }

        // --- bin -> gather bf16 weight ---
        float kvv[16];
        #pragma unroll
        for (int m = 0; m < 4; m++) {
            float4 kv4 = *(const float4*)(kvb + k0 + 4 * h + 8 * m);
            kvv[4*m+0] = kv4.x; kvv[4*m+1] = kv4.y; kvv[4*m+2] = kv4.z; kvv[4*m+3] = kv4.w;
        }
        unsigned w[16];
        #pragma unroll
        for (int r = 0; r < 16; r++) {
            float sim = sacc[r] * qv * kvv[r];
            w[r] = wt_s[binof(sim)];
            rs += bf2f((unsigned short)w[r]);
        }
        unsigned P[8], G[8];
        #pragma unroll
        for (int i = 0; i < 8; i++) P[i] = w[2*i] | (w[2*i+1] << 16);
        #pragma unroll
        for (int i = 0; i < 8; i++) G[i] = __shfl_xor(P[i], 32);

        union { unsigned u[4]; short8 v; } a0, a1;
        a0.u[0] = h ? G[2] : P[0];
        a0.u[1] = h ? G[3] : P[1];
        a0.u[2] = h ? P[2] : G[0];
        a0.u[3] = h ? P[3] : G[1];
        a1.u[0] = h ? G[6] : P[4];
        a1.u[1] = h ? G[7] : P[5];
        a1.u[2] = h ? P[6] : G[4];
        a1.u[3] = h ? P[7] : G[5];

        // --- PV: A from registers, B = Vt fragments from global ---
        {
            const unsigned short* vr0 = vb + (size_t)(c) * S + k0 + h * 8;
            short8 b0 = *(const short8*)(vr0);
            short8 b1 = *(const short8*)(vr0 + 16);
            oacc0 = __builtin_amdgcn_mfma_f32_32x32x16_bf16(a0.v, b0, oacc0, 0, 0, 0);
            oacc0 = __builtin_amdgcn_mfma_f32_32x32x16_bf16(a1.v, b1, oacc0, 0, 0, 0);
        }
        {
            const unsigned short* vr1 = vb + (size_t)(32 + c) * S + k0 + h * 8;
            short8 b0 = *(const short8*)(vr1);
            short8 b1 = *(const short8*)(vr1 + 16);
            oacc1 = __builtin_amdgcn_mfma_f32_32x32x16_bf16(a0.v, b0, oacc1, 0, 0, 0);
            oacc1 = __builtin_amdgcn_mfma_f32_32x32x16_bf16(a1.v, b1, oacc1, 0, 0, 0);
        }
    }

    rs += __shfl_xor(rs, 32);   // full per-(wave,q=c) rowsum partial

    // --- merge the 4 k-split waves through LDS ---
    for (int w = 0; w < 4; w++) {
        if (wv == w) {
            if (w == 0) {
                #pragma unroll
                for (int r = 0; r < 16; r++) {
                    int qq = (r & 3) + 8 * (r >> 2) + 4 * h;
                    zone[qq * 64 + c]      = oacc0[r];
                    zone[qq * 64 + 32 + c] = oacc1[r];
                }
                if (h == 0) rsz[c] = rs;
            } else {
                #pragma unroll
                for (int r = 0; r < 16; r++) {
                    int qq = (r & 3) + 8 * (r >> 2) + 4 * h;
                    zone[qq * 64 + c]      += oacc0[r];
                    zone[qq * 64 + 32 + c] += oacc1[r];
                }
                if (h == 0) rsz[c] += rs;
            }
        }
        __syncthreads();
    }

    // --- normalize + store ---
    int q = t >> 3, d0 = (t & 7) * 8;
    float inv = 1.0f / rsz[q];
    float* zp = &zone[q * 64 + d0];
    float4 o0 = *(float4*)(zp);
    float4 o1 = *(float4*)(zp + 4);
    o0.x *= inv; o0.y *= inv; o0.z *= inv; o0.w *= inv;
    o1.x *= inv; o1.y *= inv; o1.z *= inv; o1.w *= inv;
    float* op = out + ((size_t)bh * S + q0 + q) * D + d0;
    *(float4*)(op)     = o0;
    *(float4*)(op + 4) = o1;
}

extern "C" void kernel_launch(void* const* d_in, const int* in_sizes, int n_in,
                              void* d_out, int out_size, void* d_ws, size_t ws_size,
                              hipStream_t stream) {
    const float* Q = (const float*)d_in[0];
    const float* K = (const float*)d_in[1];
    const float* V = (const float*)d_in[2];
    float* out = (float*)d_out;

    char* w = (char*)d_ws;
    float* qinv = (float*)w;
    float* kinv = qinv + NBH * S;
    size_t off = (size_t)2 * NBH * S * sizeof(float);
    unsigned short* Qhi = (unsigned short*)(w + off); off += (size_t)NBH * S * D * 2;
    unsigned short* Qlo = (unsigned short*)(w + off); off += (size_t)NBH * S * D * 2;
    unsigned short* Khi = (unsigned short*)(w + off); off += (size_t)NBH * S * D * 2;
    unsigned short* Klo = (unsigned short*)(w + off); off += (size_t)NBH * S * D * 2;
    unsigned short* Vt  = (unsigned short*)(w + off); off += (size_t)NBH * D * S * 2;
    unsigned* hist = (unsigned*)(w + off);            off += (size_t)NBH * NWORDS * 4;
    unsigned short* wtab = (unsigned short*)(w + off); off += (size_t)NBH * NBINS * 2;

    hipMemsetAsync(hist, 0, (size_t)NBH * NWORDS * 4, stream);
    norms_kernel<<<(2 * NBH * S) / 16, 256, 0, stream>>>(Q, K, qinv, kinv, Qhi, Qlo, Khi, Klo);
    vt_kernel<<<NBH * 16, 256, 0, stream>>>(V, Vt);
    hist_kernel<<<NBH * 32, 256, 0, stream>>>(Qhi, Qlo, Khi, Klo, qinv, kinv, hist);
    table_kernel<<<NBH, 1024, 0, stream>>>(hist, wtab);
    fused_kernel<<<NBH * 32, 256, 0, stream>>>(Qhi, Qlo, Khi, Klo, qinv, kinv, wtab, Vt, out);
}